// Round 6
// baseline (403.632 us; speedup 1.0000x reference)
//
#include <hip/hip_runtime.h>
#include <hip/hip_bf16.h>
#include <stdint.h>

#define DEVINL __device__ __forceinline__

typedef unsigned short u16;
typedef __attribute__((ext_vector_type(8))) short bf16x8;   // 8 bf16 = 4 VGPRs (MFMA A/B frag)
typedef __attribute__((ext_vector_type(4))) float f32x4;    // MFMA C/D frag
typedef __attribute__((ext_vector_type(8))) unsigned short u16x8;

DEVINL u16 f2bf(float f) {               // round-to-nearest-even f32 -> bf16
  union { float f; unsigned u; } x; x.f = f;
  unsigned r = x.u + 0x7fffu + ((x.u >> 16) & 1u);
  return (u16)(r >> 16);
}
DEVINL float bf2f(u16 u) {
  union { float f; unsigned u; } x; x.u = ((unsigned)u) << 16; return x.f;
}

DEVINL void load_lds16(const u16* g, u16* l) {
  // async global->LDS, 16B per lane; LDS dest = wave-uniform base + lane*16
  __builtin_amdgcn_global_load_lds(
      (const __attribute__((address_space(1))) void*)g,
      (__attribute__((address_space(3))) void*)l, 16, 0, 0);
}

// ---------------------------------------------------------------------------
// C[M,N] = A[M,K] @ Bt[N,K]^T * scale (+ epilogue)    A,Bt bf16; C bf16 or f32
// BMODE: 0 none | 1 +bias[col] | 2 +bias[row] | 3 dual col bias split at N/2
//        4 *1/lsum[row] + bias[col] (f32 out) | 5 *1/lsum[row] (bf16 out)
//        6 E=exp(acc*scale) bf16 out + atomicAdd row sums into lsum
// ZSWZ: batch-coherent XCD remap (gridDim.z == 8): work_z = lin&7 so all
//       concurrent blocks on one XCD share one batch's panels.
// 256x256 tile, BK=32, ring-4 LDS slots, counted-vmcnt pipeline (depth 3),
// 16x16x32 MFMA (HW-verified 0 bank conflicts).
// 512 threads = 8 waves (2M x 4N), wave tile 128x64 -> acc[8][4] of f32x4.
//
// Race-freedom: iteration t reads slot t&3 after {vmcnt(8); s_barrier}:
// vmcnt(8) retires this wave's 4 loads of tile t; barrier extends to all
// waves. stage(t+3) -> slot (t-1)&3 whose readers all passed this barrier.
// One barrier per K-step; never vmcnt(0) mid-loop. LDS swizzle: 16B-block
// blk' = blk ^ ((row>>1)&3) on the GLOBAL source + on the ds_read address.
// ---------------------------------------------------------------------------
template<bool OUT_F32, int BMODE, bool ZSWZ>
__global__ __launch_bounds__(512)
void gemm256(const u16* __restrict__ A, const u16* __restrict__ Bt,
             void* __restrict__ Cv,
             const float* __restrict__ bias, const float* __restrict__ bias2,
             float* __restrict__ lsum,
             int M, int N, int K, int lda, int ldb, float scale,
             long sA, long sB, long sC)
{
  int bxs = blockIdx.x, bys = blockIdx.y, bz = blockIdx.z;
  if (ZSWZ) {
    const int lin  = blockIdx.x + gridDim.x * (blockIdx.y + gridDim.y * blockIdx.z);
    bz = lin & 7;
    const int rest = lin >> 3;
    bxs = rest % gridDim.x;
    bys = rest / gridDim.x;
  }
  A  += (size_t)bz * sA;
  Bt += (size_t)bz * sB;
  if (BMODE >= 4) lsum += (size_t)bz * M;

  const int tid  = threadIdx.x;
  const int lane = tid & 63;
  const int w    = tid >> 6;
  const int wm   = w >> 2;          // 0..1  (M direction, 128 rows each)
  const int wn   = w & 3;           // 0..3  (N direction, 64 cols each)
  const int brow = bys * 256;
  const int bcol = bxs * 256;

  __shared__ u16 lds[4][2][256 * 32];   // [slot][A/B][row*32+col]  128 KiB

  const u16* gA = A  + (size_t)brow * lda;
  const u16* gB = Bt + (size_t)bcol * ldb;

  // per-thread staging descriptors: 2 rounds x (A,B); 16B chunk c = r*512+tid
  int c8[2], soffA[2], soffB[2];
#pragma unroll
  for (int r = 0; r < 2; ++r) {
    const int c    = r * 512 + tid;
    const int row  = c >> 2;
    const int blk  = c & 3;
    const int sblk = blk ^ ((row >> 1) & 3);   // inverse swizzle on source
    c8[r]    = c * 8;
    soffA[r] = row * lda + sblk * 8;
    soffB[r] = row * ldb + sblk * 8;
  }
  const int NT = K >> 5;

  f32x4 acc[8][4] = {};

  // prologue: stage tiles 0..2
#pragma unroll
  for (int tt = 0; tt < 3; ++tt) {
    const int kt = tt * 32;
#pragma unroll
    for (int r = 0; r < 2; ++r) load_lds16(gA + soffA[r] + kt, &lds[tt][0][c8[r]]);
#pragma unroll
    for (int r = 0; r < 2; ++r) load_lds16(gB + soffB[r] + kt, &lds[tt][1][c8[r]]);
  }
  __builtin_amdgcn_sched_barrier(0);

  // read addressing (HW-verified conflict-free): quarter kq = lane>>4 picks
  // k-block; rsw = (kq ^ ((lane>>1)&3))*8 matches the write-side swizzle.
  const int rsw   = ((lane >> 4) ^ ((lane >> 1) & 3)) * 8;
  const int arow0 = wm * 128 + (lane & 15);
  const int brow0 = wn * 64  + (lane & 15);

  for (int t = 0; t < NT; ++t) {
    if (t < NT - 2)       asm volatile("s_waitcnt vmcnt(8)" ::: "memory");
    else if (t == NT - 2) asm volatile("s_waitcnt vmcnt(4)" ::: "memory");
    else                  asm volatile("s_waitcnt vmcnt(0)" ::: "memory");
    __builtin_amdgcn_s_barrier();
    __builtin_amdgcn_sched_barrier(0);

    const u16* la = lds[t & 3][0];
    const u16* lb = lds[t & 3][1];
    bf16x8 av[8], bv[4];
#pragma unroll
    for (int m = 0; m < 8; ++m)
      av[m] = *(const bf16x8*)&la[(arow0 + m * 16) * 32 + rsw];
#pragma unroll
    for (int n = 0; n < 4; ++n)
      bv[n] = *(const bf16x8*)&lb[(brow0 + n * 16) * 32 + rsw];

    if (t + 3 < NT) {                      // stage tile t+3 into slot (t-1)&3
      const int kt = (t + 3) * 32, sl = (t + 3) & 3;
#pragma unroll
      for (int r = 0; r < 2; ++r) load_lds16(gA + soffA[r] + kt, &lds[sl][0][c8[r]]);
#pragma unroll
      for (int r = 0; r < 2; ++r) load_lds16(gB + soffB[r] + kt, &lds[sl][1][c8[r]]);
    }

    __builtin_amdgcn_s_setprio(1);
#pragma unroll
    for (int m = 0; m < 8; ++m)
#pragma unroll
      for (int n = 0; n < 4; ++n)
        acc[m][n] = __builtin_amdgcn_mfma_f32_16x16x32_bf16(av[m], bv[n], acc[m][n], 0, 0, 0);
    __builtin_amdgcn_s_setprio(0);
  }

  // epilogue: C/D layout col = lane&15, row = (lane>>4)*4 + j  [m89-verified]
  float* Cf = (float*)Cv + (size_t)bz * sC;
  u16*   Cb = (u16*)Cv   + (size_t)bz * sC;
  const int r0base  = brow + wm * 128 + ((lane >> 4) << 2);
  const int colbase = bcol + wn * 64  + (lane & 15);
#pragma unroll
  for (int m = 0; m < 8; ++m) {
    if (BMODE == 6) {
      // write E = exp(acc*scale) and accumulate per-row sums into lsum.
      // rows for this (m): same across the 16 lanes of a (lane>>4) subgroup;
      // shfl_xor over masks 1,2,4,8 reduces the 64 cols this wave owns.
#pragma unroll
      for (int j = 0; j < 4; ++j) {
        const int row = r0base + m * 16 + j;
        float rp = 0.f;
#pragma unroll
        for (int n = 0; n < 4; ++n) {
          const int col = colbase + n * 16;
          const float e = __expf(acc[m][n][j] * scale);
          const u16 eb = f2bf(e);
          Cb[(size_t)row * N + col] = eb;
          rp += bf2f(eb);
        }
        rp += __shfl_xor(rp, 1);
        rp += __shfl_xor(rp, 2);
        rp += __shfl_xor(rp, 4);
        rp += __shfl_xor(rp, 8);
        if ((lane & 15) == 0) atomicAdd(&lsum[row], rp);
      }
    } else {
      float invl_j[4];
      if (BMODE == 4 || BMODE == 5) {
#pragma unroll
        for (int j = 0; j < 4; ++j)
          invl_j[j] = 1.0f / lsum[r0base + m * 16 + j];
      }
      const int r0 = r0base + m * 16;
#pragma unroll
      for (int n = 0; n < 4; ++n) {
        const int col = colbase + n * 16;
        float badd = 0.f;
        if (BMODE == 1 || BMODE == 4) badd = bias[col];
        if (BMODE == 3) badd = (col < (N >> 1)) ? bias[col] : bias2[col - (N >> 1)];
#pragma unroll
        for (int j = 0; j < 4; ++j) {
          const int row = r0 + j;
          float v = acc[m][n][j] * scale;
          if (BMODE == 4 || BMODE == 5) v *= invl_j[j];
          v += badd;
          if (BMODE == 2) v += bias[row];
          if (OUT_F32) Cf[(size_t)row * N + col] = v;
          else         Cb[(size_t)row * N + col] = f2bf(v);
        }
      }
    }
  }
}

// ---------------------------------------------------------------------------
__global__ __launch_bounds__(256)
void cvt_f32_bf16(const float* __restrict__ in, u16* __restrict__ out, int n8)
{
  const int i = blockIdx.x * 256 + threadIdx.x;
  if (i >= n8) return;
  const float4* in4 = (const float4*)in;
  float4 a = in4[2 * i], b = in4[2 * i + 1];
  u16x8 o;
  o[0] = f2bf(a.x); o[1] = f2bf(a.y); o[2] = f2bf(a.z); o[3] = f2bf(a.w);
  o[4] = f2bf(b.x); o[5] = f2bf(b.y); o[6] = f2bf(b.z); o[7] = f2bf(b.w);
  ((u16x8*)out)[i] = o;
}

// transpose + convert 1024x1024 fp32 -> bf16 (Tj[e][d] = Wj[d][e])
__global__ __launch_bounds__(256)
void transpose_cvt(const float* __restrict__ W0, const float* __restrict__ W1,
                   const float* __restrict__ W2, const float* __restrict__ W3,
                   u16* __restrict__ T0, u16* __restrict__ T1,
                   u16* __restrict__ T2, u16* __restrict__ T3)
{
  const float* W = blockIdx.z == 0 ? W0 : blockIdx.z == 1 ? W1 : blockIdx.z == 2 ? W2 : W3;
  u16*         T = blockIdx.z == 0 ? T0 : blockIdx.z == 1 ? T1 : blockIdx.z == 2 ? T2 : T3;
  __shared__ float tile[32][33];
  const int d0 = blockIdx.y * 32, e0 = blockIdx.x * 32;
  const int tx = threadIdx.x, ty = threadIdx.y;
#pragma unroll
  for (int r = ty; r < 32; r += 8)
    tile[r][tx] = W[(size_t)(d0 + r) * 1024 + e0 + tx];
  __syncthreads();
#pragma unroll
  for (int r = ty; r < 32; r += 8)
    T[(size_t)(e0 + r) * 1024 + d0 + tx] = f2bf(tile[tx][r]);
}

// b2[e] = sum_c bv[c] * Wo[c][e] + bo[e]   (1024 outputs, f32)
// 16 blocks x 256 threads: block owns 64 e-columns; threads stride rows in
// groups of 4 (tid>>6), coalesced 64x4B row segments; LDS reduce across groups.
__global__ __launch_bounds__(256)
void make_b2(const float* __restrict__ bv, const float* __restrict__ Wo,
             const float* __restrict__ bo, float* __restrict__ b2)
{
  const int el = threadIdx.x & 63;
  const int e  = blockIdx.x * 64 + el;
  const int cg = threadIdx.x >> 6;            // 0..3
  float s = 0.f;
  for (int c = cg; c < 1024; c += 4)
    s += bv[c] * Wo[(size_t)c * 1024 + e];
  __shared__ float red[4][64];
  red[cg][el] = s;
  __syncthreads();
  if (cg == 0)
    b2[e] = red[0][el] + red[1][el] + red[2][el] + red[3][el] + bo[e];
}

__global__ __launch_bounds__(256)
void zero_f32(float* __restrict__ p, int n)
{
  const int i = blockIdx.x * 256 + threadIdx.x;
  if (i < n) p[i] = 0.f;
}

// ---------------------------------------------------------------------------
extern "C" void kernel_launch(void* const* d_in, const int* in_sizes, int n_in,
                              void* d_out, int out_size, void* d_ws, size_t ws_size,
                              hipStream_t stream)
{
  const float* X  = (const float*)d_in[0];
  const float* Wq = (const float*)d_in[1];
  const float* bq = (const float*)d_in[2];
  const float* Wk = (const float*)d_in[3];
  const float* bk = (const float*)d_in[4];
  const float* Wv = (const float*)d_in[5];
  const float* bv = (const float*)d_in[6];
  const float* Wo = (const float*)d_in[7];
  const float* bo = (const float*)d_in[8];

  constexpr int B = 8, N = 2048, D = 1024;
  constexpr size_t TOK = (size_t)B * N;        // 16384
  constexpr size_t SZX = TOK * D;              // 16,777,216 elems
  constexpr size_t SZW = (size_t)D * D;

  const size_t FUSED_BYTES = (5 * SZX + 5 * SZW + 34816) * sizeof(u16);   // ~178 MB

  if (ws_size >= FUSED_BYTES) {
    // ---- fused path: out = E @ (X@(Wv@Wo))^T / l + (bv@Wo + bo) ----
    u16* QK  = (u16*)d_ws;            // [16384][2048]: cols 0..1023 Q, rest K
    u16* Vpt = QK  + 2 * SZX;         // V'^T = (X@W2)^T  [B][D][N]
    u16* E   = Vpt + SZX;             // exp(scores) bf16 [B][N][N]
    u16* Xb  = E;                     // overlay: Xb dead before E is written
    u16* Wqt = E   + 2 * SZX;
    u16* Wkt = Wqt + SZW;
    u16* Wot = Wkt + SZW;
    u16* Wvb = Wot + SZW;             // Wv bf16, NOT transposed
    u16* W2t = Wvb + SZW;             // (Wv@Wo)^T bf16
    float* b2 = (float*)(W2t + SZW);  // 1024 f32
    float* l  = b2 + 1024;            // 16384 f32 row sums

    cvt_f32_bf16<<<dim3((unsigned)(SZX / 8 / 256)), 256, 0, stream>>>(X, Xb, (int)(SZX / 8));
    cvt_f32_bf16<<<dim3((unsigned)(SZW / 8 / 256)), 256, 0, stream>>>(Wv, Wvb, (int)(SZW / 8));
    transpose_cvt<<<dim3(32, 32, 4), dim3(32, 8), 0, stream>>>(Wq, Wk, Wv, Wo, Wqt, Wkt, W2t, Wot);
    make_b2<<<dim3(16), 256, 0, stream>>>(bv, Wo, bo, b2);
    zero_f32<<<dim3(64), 256, 0, stream>>>(l, (int)TOK);

    // W2t[e][d] = sum_c Wot[e][c] * Wvb[d][c]  ->  W2t = (Wv@Wo)^T
    gemm256<false, 0, false><<<dim3(4, 4, 1), 512, 0, stream>>>(
        Wot, Wvb, W2t, nullptr, nullptr, nullptr, D, D, D, D, D, 1.f, 0, 0, 0);

    // fused Q,K projection: [16384,2048] = X @ [Wq|Wk] (+ bq|bk)
    gemm256<false, 3, false><<<dim3(8, 64, 1), 512, 0, stream>>>(
        Xb, Wqt, QK, bq, bk, nullptr, (int)TOK, 2 * D, D, D, D, 1.f, 0, 0, 0);

    // V'^T[b] = W2t @ Xb[b]^T   [D, N] per batch (no bias)
    gemm256<false, 0, true><<<dim3(8, 4, 8), 512, 0, stream>>>(
        W2t, Xb, Vpt, nullptr, nullptr, nullptr, D, N, D, D, D, 1.f,
        0, (long)N * D, (long)D * N);

    // E[b] = exp(Q[b] @ K[b]^T / 32), row sums into l
    gemm256<false, 6, true><<<dim3(8, 8, 8), 512, 0, stream>>>(
        QK, QK + D, E, nullptr, nullptr, l, N, N, D, 2 * D, 2 * D, 0.03125f,
        (long)N * 2 * D, (long)N * 2 * D, (long)N * N);

    // out[b] = (E[b] @ V'^T[b]^T) / l + b2   f32 -> d_out
    gemm256<true, 4, true><<<dim3(4, 8, 8), 512, 0, stream>>>(
        E, Vpt, d_out, b2, nullptr, l, N, D, N, N, N, 1.f,
        (long)N * N, (long)D * N, (long)N * D);
  } else {
    // ---- fallback (round-4 flow + softmax-free l scheme) ----
    if (ws_size < (4 * SZX + 4 * SZW) * sizeof(u16) + 65536) return;
    u16* Xb  = (u16*)d_ws;            // X bf16; later reused as attn_out (AO)
    u16* Wqt = Xb  + SZX;
    u16* Wkt = Wqt + SZW;
    u16* Wvt = Wkt + SZW;
    u16* Wot = Wvt + SZW;
    u16* QK  = Wot + SZW;
    u16* Vt  = QK  + 2 * SZX;         // [B][D][N]
    float* l = (float*)(Vt + SZX);    // 16384 f32
    u16* E   = (u16*)d_out;           // exp(scores) bf16 in d_out
    u16* AO  = Xb;

    cvt_f32_bf16<<<dim3((unsigned)(SZX / 8 / 256)), 256, 0, stream>>>(X, Xb, (int)(SZX / 8));
    transpose_cvt<<<dim3(32, 32, 4), dim3(32, 8), 0, stream>>>(Wq, Wk, Wv, Wo, Wqt, Wkt, Wvt, Wot);

    gemm256<false, 3, false><<<dim3(8, 64, 1), 512, 0, stream>>>(
        Xb, Wqt, QK, bq, bk, nullptr, (int)TOK, 2 * D, D, D, D, 1.f, 0, 0, 0);

    gemm256<false, 2, true><<<dim3(8, 4, 8), 512, 0, stream>>>(
        Wvt, Xb, Vt, bv, nullptr, nullptr, D, N, D, D, D, 1.f,
        0, (long)N * D, (long)D * N);

    zero_f32<<<dim3(64), 256, 0, stream>>>(l, (int)TOK);

    gemm256<false, 6, true><<<dim3(8, 8, 8), 512, 0, stream>>>(
        QK, QK + D, E, nullptr, nullptr, l, N, N, D, 2 * D, 2 * D, 0.03125f,
        (long)N * 2 * D, (long)N * 2 * D, (long)N * N);

    gemm256<false, 5, true><<<dim3(4, 8, 8), 512, 0, stream>>>(
        E, Vt, AO, nullptr, nullptr, l, N, D, N, N, N, 1.f,
        (long)N * N, (long)D * N, (long)N * D);

    gemm256<true, 1, false><<<dim3(4, 64, 1), 512, 0, stream>>>(
        AO, Wot, d_out, bo, nullptr, nullptr, (int)TOK, D, D, D, D, 1.f, 0, 0, 0);
  }
}

// Round 7
// 394.375 us; speedup vs baseline: 1.0235x; 1.0235x over previous
//
#include <hip/hip_runtime.h>
#include <hip/hip_bf16.h>
#include <stdint.h>

#define DEVINL __device__ __forceinline__

typedef unsigned short u16;
typedef __attribute__((ext_vector_type(8))) short bf16x8;   // 8 bf16 = 4 VGPRs (MFMA A/B frag)
typedef __attribute__((ext_vector_type(4))) float f32x4;    // MFMA C/D frag
typedef __attribute__((ext_vector_type(8))) unsigned short u16x8;

DEVINL u16 f2bf(float f) {               // round-to-nearest-even f32 -> bf16
  union { float f; unsigned u; } x; x.f = f;
  unsigned r = x.u + 0x7fffu + ((x.u >> 16) & 1u);
  return (u16)(r >> 16);
}
DEVINL float bf2f(u16 u) {
  union { float f; unsigned u; } x; x.u = ((unsigned)u) << 16; return x.f;
}

DEVINL void load_lds16(const u16* g, u16* l) {
  // async global->LDS, 16B per lane; LDS dest = wave-uniform base + lane*16
  __builtin_amdgcn_global_load_lds(
      (const __attribute__((address_space(1))) void*)g,
      (__attribute__((address_space(3))) void*)l, 16, 0, 0);
}

// ---------------------------------------------------------------------------
// C[M,N] = A[M,K] @ Bt[N,K]^T * scale (+ epilogue)    A,Bt bf16; C bf16 or f32
// BMODE: 0 none | 1 +bias[col] | 2 +bias[row] | 3 dual col bias split at N/2
//        4 *1/lsum[row] + bias[col] (f32 out) | 5 *1/lsum[row] (bf16 out)
//        6 E=exp(acc*scale) bf16 out + atomicAdd row sums into lsum
// ZSWZ: batch-coherent XCD remap (gridDim.z == 8): work_z = lin&7 so all
//       concurrent blocks on one XCD share one batch's panels.
// Split-K use: pass sA=sB=K_chunk (element offset into the K dim), sC = slab
// stride, gridDim.z = n_splits, K = K_chunk -> per-z partial products.
// 256x256 tile, BK=32, ring-4 LDS slots, counted-vmcnt pipeline (depth 3),
// 16x16x32 MFMA (HW-verified 0 bank conflicts).
// 512 threads = 8 waves (2M x 4N), wave tile 128x64 -> acc[8][4] of f32x4.
//
// Race-freedom: iteration t reads slot t&3 after {vmcnt(8); s_barrier}:
// vmcnt(8) retires this wave's 4 loads of tile t; barrier extends to all
// waves. stage(t+3) -> slot (t-1)&3 whose readers all passed this barrier.
// One barrier per K-step; never vmcnt(0) mid-loop. LDS swizzle: 16B-block
// blk' = blk ^ ((row>>1)&3) on the GLOBAL source + on the ds_read address.
// ---------------------------------------------------------------------------
template<bool OUT_F32, int BMODE, bool ZSWZ>
__global__ __launch_bounds__(512)
void gemm256(const u16* __restrict__ A, const u16* __restrict__ Bt,
             void* __restrict__ Cv,
             const float* __restrict__ bias, const float* __restrict__ bias2,
             float* __restrict__ lsum,
             int M, int N, int K, int lda, int ldb, float scale,
             long sA, long sB, long sC)
{
  int bxs = blockIdx.x, bys = blockIdx.y, bz = blockIdx.z;
  if (ZSWZ) {
    const int lin  = blockIdx.x + gridDim.x * (blockIdx.y + gridDim.y * blockIdx.z);
    bz = lin & 7;
    const int rest = lin >> 3;
    bxs = rest % gridDim.x;
    bys = rest / gridDim.x;
  }
  A  += (size_t)bz * sA;
  Bt += (size_t)bz * sB;
  if (BMODE >= 4) lsum += (size_t)bz * M;

  const int tid  = threadIdx.x;
  const int lane = tid & 63;
  const int w    = tid >> 6;
  const int wm   = w >> 2;          // 0..1  (M direction, 128 rows each)
  const int wn   = w & 3;           // 0..3  (N direction, 64 cols each)
  const int brow = bys * 256;
  const int bcol = bxs * 256;

  __shared__ u16 lds[4][2][256 * 32];   // [slot][A/B][row*32+col]  128 KiB

  const u16* gA = A  + (size_t)brow * lda;
  const u16* gB = Bt + (size_t)bcol * ldb;

  // per-thread staging descriptors: 2 rounds x (A,B); 16B chunk c = r*512+tid
  int c8[2], soffA[2], soffB[2];
#pragma unroll
  for (int r = 0; r < 2; ++r) {
    const int c    = r * 512 + tid;
    const int row  = c >> 2;
    const int blk  = c & 3;
    const int sblk = blk ^ ((row >> 1) & 3);   // inverse swizzle on source
    c8[r]    = c * 8;
    soffA[r] = row * lda + sblk * 8;
    soffB[r] = row * ldb + sblk * 8;
  }
  const int NT = K >> 5;

  f32x4 acc[8][4] = {};

  // prologue: stage tiles 0..2
#pragma unroll
  for (int tt = 0; tt < 3; ++tt) {
    const int kt = tt * 32;
#pragma unroll
    for (int r = 0; r < 2; ++r) load_lds16(gA + soffA[r] + kt, &lds[tt][0][c8[r]]);
#pragma unroll
    for (int r = 0; r < 2; ++r) load_lds16(gB + soffB[r] + kt, &lds[tt][1][c8[r]]);
  }
  __builtin_amdgcn_sched_barrier(0);

  // read addressing (HW-verified conflict-free): quarter kq = lane>>4 picks
  // k-block; rsw = (kq ^ ((lane>>1)&3))*8 matches the write-side swizzle.
  const int rsw   = ((lane >> 4) ^ ((lane >> 1) & 3)) * 8;
  const int arow0 = wm * 128 + (lane & 15);
  const int brow0 = wn * 64  + (lane & 15);

  for (int t = 0; t < NT; ++t) {
    if (t < NT - 2)       asm volatile("s_waitcnt vmcnt(8)" ::: "memory");
    else if (t == NT - 2) asm volatile("s_waitcnt vmcnt(4)" ::: "memory");
    else                  asm volatile("s_waitcnt vmcnt(0)" ::: "memory");
    __builtin_amdgcn_s_barrier();
    __builtin_amdgcn_sched_barrier(0);

    const u16* la = lds[t & 3][0];
    const u16* lb = lds[t & 3][1];
    bf16x8 av[8], bv[4];
#pragma unroll
    for (int m = 0; m < 8; ++m)
      av[m] = *(const bf16x8*)&la[(arow0 + m * 16) * 32 + rsw];
#pragma unroll
    for (int n = 0; n < 4; ++n)
      bv[n] = *(const bf16x8*)&lb[(brow0 + n * 16) * 32 + rsw];

    if (t + 3 < NT) {                      // stage tile t+3 into slot (t-1)&3
      const int kt = (t + 3) * 32, sl = (t + 3) & 3;
#pragma unroll
      for (int r = 0; r < 2; ++r) load_lds16(gA + soffA[r] + kt, &lds[sl][0][c8[r]]);
#pragma unroll
      for (int r = 0; r < 2; ++r) load_lds16(gB + soffB[r] + kt, &lds[sl][1][c8[r]]);
    }

    __builtin_amdgcn_s_setprio(1);
#pragma unroll
    for (int m = 0; m < 8; ++m)
#pragma unroll
      for (int n = 0; n < 4; ++n)
        acc[m][n] = __builtin_amdgcn_mfma_f32_16x16x32_bf16(av[m], bv[n], acc[m][n], 0, 0, 0);
    __builtin_amdgcn_s_setprio(0);
  }

  // epilogue: C/D layout col = lane&15, row = (lane>>4)*4 + j  [m89-verified]
  float* Cf = (float*)Cv + (size_t)bz * sC;
  u16*   Cb = (u16*)Cv   + (size_t)bz * sC;
  const int r0base  = brow + wm * 128 + ((lane >> 4) << 2);
  const int colbase = bcol + wn * 64  + (lane & 15);
#pragma unroll
  for (int m = 0; m < 8; ++m) {
    if (BMODE == 6) {
      // write E = exp(acc*scale) and accumulate per-row sums into lsum.
#pragma unroll
      for (int j = 0; j < 4; ++j) {
        const int row = r0base + m * 16 + j;
        float rp = 0.f;
#pragma unroll
        for (int n = 0; n < 4; ++n) {
          const int col = colbase + n * 16;
          const float e = __expf(acc[m][n][j] * scale);
          const u16 eb = f2bf(e);
          Cb[(size_t)row * N + col] = eb;
          rp += bf2f(eb);
        }
        rp += __shfl_xor(rp, 1);
        rp += __shfl_xor(rp, 2);
        rp += __shfl_xor(rp, 4);
        rp += __shfl_xor(rp, 8);
        if ((lane & 15) == 0) atomicAdd(&lsum[row], rp);
      }
    } else {
      float invl_j[4];
      if (BMODE == 4 || BMODE == 5) {
#pragma unroll
        for (int j = 0; j < 4; ++j)
          invl_j[j] = 1.0f / lsum[r0base + m * 16 + j];
      }
      const int r0 = r0base + m * 16;
#pragma unroll
      for (int n = 0; n < 4; ++n) {
        const int col = colbase + n * 16;
        float badd = 0.f;
        if (BMODE == 1 || BMODE == 4) badd = bias[col];
        if (BMODE == 3) badd = (col < (N >> 1)) ? bias[col] : bias2[col - (N >> 1)];
#pragma unroll
        for (int j = 0; j < 4; ++j) {
          const int row = r0 + j;
          float v = acc[m][n][j] * scale;
          if (BMODE == 4 || BMODE == 5) v *= invl_j[j];
          v += badd;
          if (BMODE == 2) v += bias[row];
          if (OUT_F32) Cf[(size_t)row * N + col] = v;
          else         Cb[(size_t)row * N + col] = f2bf(v);
        }
      }
    }
  }
}

// ---------------------------------------------------------------------------
__global__ __launch_bounds__(256)
void cvt_f32_bf16(const float* __restrict__ in, u16* __restrict__ out, int n8)
{
  const int i = blockIdx.x * 256 + threadIdx.x;
  if (i >= n8) return;
  const float4* in4 = (const float4*)in;
  float4 a = in4[2 * i], b = in4[2 * i + 1];
  u16x8 o;
  o[0] = f2bf(a.x); o[1] = f2bf(a.y); o[2] = f2bf(a.z); o[3] = f2bf(a.w);
  o[4] = f2bf(b.x); o[5] = f2bf(b.y); o[6] = f2bf(b.z); o[7] = f2bf(b.w);
  ((u16x8*)out)[i] = o;
}

// out[i] = bf16(p[i] + p[i+n] + p[i+2n] + p[i+3n])  — split-K partial reduce
__global__ __launch_bounds__(256)
void reduce4_cvt(const float* __restrict__ p, u16* __restrict__ out, int n4)
{
  const int i = blockIdx.x * 256 + threadIdx.x;
  if (i >= n4) return;
  const float4* p4 = (const float4*)p;
  const int n = n4 << 2;
  float4 a = p4[i], b = p4[i + (n4)], c = p4[i + 2 * (size_t)n4], d = p4[i + 3 * (size_t)n4];
  (void)n;
  ushort4 o;
  o.x = f2bf(a.x + b.x + c.x + d.x);
  o.y = f2bf(a.y + b.y + c.y + d.y);
  o.z = f2bf(a.z + b.z + c.z + d.z);
  o.w = f2bf(a.w + b.w + c.w + d.w);
  ((ushort4*)out)[i] = o;
}

// transpose + convert 1024x1024 fp32 -> bf16 (Tj[e][d] = Wj[d][e])
__global__ __launch_bounds__(256)
void transpose_cvt(const float* __restrict__ W0, const float* __restrict__ W1,
                   const float* __restrict__ W2, const float* __restrict__ W3,
                   u16* __restrict__ T0, u16* __restrict__ T1,
                   u16* __restrict__ T2, u16* __restrict__ T3)
{
  const float* W = blockIdx.z == 0 ? W0 : blockIdx.z == 1 ? W1 : blockIdx.z == 2 ? W2 : W3;
  u16*         T = blockIdx.z == 0 ? T0 : blockIdx.z == 1 ? T1 : blockIdx.z == 2 ? T2 : T3;
  __shared__ float tile[32][33];
  const int d0 = blockIdx.y * 32, e0 = blockIdx.x * 32;
  const int tx = threadIdx.x, ty = threadIdx.y;
#pragma unroll
  for (int r = ty; r < 32; r += 8)
    tile[r][tx] = W[(size_t)(d0 + r) * 1024 + e0 + tx];
  __syncthreads();
#pragma unroll
  for (int r = ty; r < 32; r += 8)
    T[(size_t)(e0 + r) * 1024 + d0 + tx] = f2bf(tile[tx][r]);
}

// b2[e] = sum_c bv[c] * Wo[c][e] + bo[e]   (1024 outputs, f32)
// 16 blocks x 256 threads: block owns 64 e-columns; thread groups stride rows.
__global__ __launch_bounds__(256)
void make_b2(const float* __restrict__ bv, const float* __restrict__ Wo,
             const float* __restrict__ bo, float* __restrict__ b2)
{
  const int el = threadIdx.x & 63;
  const int e  = blockIdx.x * 64 + el;
  const int cg = threadIdx.x >> 6;            // 0..3
  float s = 0.f;
  for (int c = cg; c < 1024; c += 4)
    s += bv[c] * Wo[(size_t)c * 1024 + e];
  __shared__ float red[4][64];
  red[cg][el] = s;
  __syncthreads();
  if (cg == 0)
    b2[e] = red[0][el] + red[1][el] + red[2][el] + red[3][el] + bo[e];
}

__global__ __launch_bounds__(256)
void zero_f32(float* __restrict__ p, int n)
{
  const int i = blockIdx.x * 256 + threadIdx.x;
  if (i < n) p[i] = 0.f;
}

// ---------------------------------------------------------------------------
extern "C" void kernel_launch(void* const* d_in, const int* in_sizes, int n_in,
                              void* d_out, int out_size, void* d_ws, size_t ws_size,
                              hipStream_t stream)
{
  const float* X  = (const float*)d_in[0];
  const float* Wq = (const float*)d_in[1];
  const float* bq = (const float*)d_in[2];
  const float* Wk = (const float*)d_in[3];
  const float* bk = (const float*)d_in[4];
  const float* Wv = (const float*)d_in[5];
  const float* bv = (const float*)d_in[6];
  const float* Wo = (const float*)d_in[7];
  const float* bo = (const float*)d_in[8];

  constexpr int B = 8, N = 2048, D = 1024;
  constexpr size_t TOK = (size_t)B * N;        // 16384
  constexpr size_t SZX = TOK * D;              // 16,777,216 elems
  constexpr size_t SZW = (size_t)D * D;

  const size_t FUSED_BYTES = (5 * SZX + 5 * SZW + 34816) * sizeof(u16);   // ~178 MB

  if (ws_size >= FUSED_BYTES) {
    // ---- fused path: out = E @ (X@(Wv@Wo))^T / l + (bv@Wo + bo) ----
    u16* QK  = (u16*)d_ws;            // [16384][2048]: cols 0..1023 Q, rest K
    u16* Vpt = QK  + 2 * SZX;         // V'^T = (X@W2)^T  [B][D][N]
    u16* E   = Vpt + SZX;             // exp(scores) bf16 [B][N][N]
    u16* Xb  = E;                     // overlay: Xb dead before E is written
    u16* Wqt = E   + 2 * SZX;
    u16* Wkt = Wqt + SZW;
    u16* Wot = Wkt + SZW;
    u16* Wvb = Wot + SZW;             // Wv bf16, NOT transposed
    u16* W2t = Wvb + SZW;             // (Wv@Wo)^T bf16
    float* b2 = (float*)(W2t + SZW);  // 1024 f32
    float* l  = b2 + 1024;            // 16384 f32 row sums
    float* W2f = (float*)QK;          // 4 x SZW f32 split-K partials (QK dead)

    cvt_f32_bf16<<<dim3((unsigned)(SZX / 8 / 256)), 256, 0, stream>>>(X, Xb, (int)(SZX / 8));
    cvt_f32_bf16<<<dim3((unsigned)(SZW / 8 / 256)), 256, 0, stream>>>(Wv, Wvb, (int)(SZW / 8));
    transpose_cvt<<<dim3(32, 32, 4), dim3(32, 8), 0, stream>>>(Wq, Wk, Wv, Wo, Wqt, Wkt, W2t, Wot);
    make_b2<<<dim3(16), 256, 0, stream>>>(bv, Wo, bo, b2);
    zero_f32<<<dim3(64), 256, 0, stream>>>(l, (int)TOK);

    // W2 split-K x4: partial[s][e][d] = sum_{c in s-th 256-chunk} Wot[e][c]*Wvb[d][c]
    // (64 blocks instead of 16 -> not CU-starved), then reduce+cvt -> W2t
    gemm256<true, 0, false><<<dim3(4, 4, 4), 512, 0, stream>>>(
        Wot, Wvb, W2f, nullptr, nullptr, nullptr, D, D, 256, D, D, 1.f,
        256, 256, (long)SZW);
    reduce4_cvt<<<dim3((unsigned)(SZW / 4 / 256)), 256, 0, stream>>>(W2f, W2t, (int)(SZW / 4));

    // fused Q,K projection: [16384,2048] = X @ [Wq|Wk] (+ bq|bk)  (overwrites W2f)
    gemm256<false, 3, false><<<dim3(8, 64, 1), 512, 0, stream>>>(
        Xb, Wqt, QK, bq, bk, nullptr, (int)TOK, 2 * D, D, D, D, 1.f, 0, 0, 0);

    // V'^T[b] = W2t @ Xb[b]^T   [D, N] per batch (no bias)
    gemm256<false, 0, true><<<dim3(8, 4, 8), 512, 0, stream>>>(
        W2t, Xb, Vpt, nullptr, nullptr, nullptr, D, N, D, D, D, 1.f,
        0, (long)N * D, (long)D * N);

    // E[b] = exp(Q[b] @ K[b]^T / 32), row sums into l  (E overlays dead Xb)
    gemm256<false, 6, true><<<dim3(8, 8, 8), 512, 0, stream>>>(
        QK, QK + D, E, nullptr, nullptr, l, N, N, D, 2 * D, 2 * D, 0.03125f,
        (long)N * 2 * D, (long)N * 2 * D, (long)N * N);

    // out[b] = (E[b] @ V'^T[b]^T) / l + b2   f32 -> d_out
    gemm256<true, 4, true><<<dim3(4, 8, 8), 512, 0, stream>>>(
        E, Vpt, d_out, b2, nullptr, l, N, D, N, N, N, 1.f,
        (long)N * N, (long)D * N, (long)N * D);
  } else {
    // ---- fallback (round-4 flow + softmax-free l scheme) ----
    if (ws_size < (4 * SZX + 4 * SZW) * sizeof(u16) + 65536) return;
    u16* Xb  = (u16*)d_ws;            // X bf16; later reused as attn_out (AO)
    u16* Wqt = Xb  + SZX;
    u16* Wkt = Wqt + SZW;
    u16* Wvt = Wkt + SZW;
    u16* Wot = Wvt + SZW;
    u16* QK  = Wot + SZW;
    u16* Vt  = QK  + 2 * SZX;         // [B][D][N]
    float* l = (float*)(Vt + SZX);    // 16384 f32
    u16* E   = (u16*)d_out;           // exp(scores) bf16 in d_out
    u16* AO  = Xb;

    cvt_f32_bf16<<<dim3((unsigned)(SZX / 8 / 256)), 256, 0, stream>>>(X, Xb, (int)(SZX / 8));
    transpose_cvt<<<dim3(32, 32, 4), dim3(32, 8), 0, stream>>>(Wq, Wk, Wv, Wo, Wqt, Wkt, Wvt, Wot);

    gemm256<false, 3, false><<<dim3(8, 64, 1), 512, 0, stream>>>(
        Xb, Wqt, QK, bq, bk, nullptr, (int)TOK, 2 * D, D, D, D, 1.f, 0, 0, 0);

    gemm256<false, 2, true><<<dim3(8, 4, 8), 512, 0, stream>>>(
        Wvt, Xb, Vt, bv, nullptr, nullptr, D, N, D, D, D, 1.f,
        0, (long)N * D, (long)D * N);

    zero_f32<<<dim3(64), 256, 0, stream>>>(l, (int)TOK);

    gemm256<false, 6, true><<<dim3(8, 8, 8), 512, 0, stream>>>(
        QK, QK + D, E, nullptr, nullptr, l, N, N, D, 2 * D, 2 * D, 0.03125f,
        (long)N * 2 * D, (long)N * 2 * D, (long)N * N);

    gemm256<false, 5, true><<<dim3(4, 8, 8), 512, 0, stream>>>(
        E, Vt, AO, nullptr, nullptr, l, N, D, N, N, N, 1.f,
        (long)N * N, (long)D * N, (long)N * D);

    gemm256<true, 1, false><<<dim3(4, 64, 1), 512, 0, stream>>>(
        AO, Wot, d_out, bo, nullptr, nullptr, (int)TOK, D, D, D, D, 1.f, 0, 0, 0);
  }
}

// Round 8
// 376.823 us; speedup vs baseline: 1.0711x; 1.0466x over previous
//
#include <hip/hip_runtime.h>
#include <hip/hip_bf16.h>
#include <stdint.h>

#define DEVINL __device__ __forceinline__

typedef unsigned short u16;
typedef __attribute__((ext_vector_type(8))) short bf16x8;   // 8 bf16 = 4 VGPRs (MFMA A/B frag)
typedef __attribute__((ext_vector_type(4))) float f32x4;    // MFMA C/D frag
typedef __attribute__((ext_vector_type(8))) unsigned short u16x8;

DEVINL u16 f2bf(float f) {               // round-to-nearest-even f32 -> bf16
  union { float f; unsigned u; } x; x.f = f;
  unsigned r = x.u + 0x7fffu + ((x.u >> 16) & 1u);
  return (u16)(r >> 16);
}
DEVINL float bf2f(u16 u) {
  union { float f; unsigned u; } x; x.u = ((unsigned)u) << 16; return x.f;
}

DEVINL void load_lds16(const u16* g, u16* l) {
  // async global->LDS, 16B per lane; LDS dest = wave-uniform base + lane*16
  __builtin_amdgcn_global_load_lds(
      (const __attribute__((address_space(1))) void*)g,
      (__attribute__((address_space(3))) void*)l, 16, 0, 0);
}

// ---------------------------------------------------------------------------
// C[M,N] = A[M,K] @ Bt[N,K]^T * scale (+ epilogue)    A,Bt bf16; C bf16 or f32
// BMODE: 0 none | 1 +bias[col] | 2 +bias[row] | 3 dual col bias split at N/2
//        4 *1/lsum[row] + bias[col] (f32 out) | 5 *1/lsum[row] (bf16 out)
//        6 E=exp(acc*scale) bf16 out + atomicAdd row sums into lsum
// SWZ:   0 none | 1 batch-coherent XCD remap (needs gridDim.z == 8): work_z =
//        lin&7 so concurrent blocks on one XCD share one batch's panels |
//        2 flat xy chunk remap (needs (gx*gy)%8==0, gz==1): same-A-panel
//        neighbors land on one XCD's L2.
// Split-K use: pass sA=sB=K_chunk, sC = slab stride, gridDim.z = n_splits.
// 256x256 tile, BK=32, ring-4 LDS slots, counted-vmcnt pipeline (depth 3),
// 16x16x32 MFMA (HW-verified 0 bank conflicts).
// 512 threads = 8 waves (2M x 4N), wave tile 128x64 -> acc[8][4] of f32x4.
//
// Race-freedom: iteration t reads slot t&3 after {vmcnt(8); s_barrier}:
// vmcnt(8) retires this wave's 4 loads of tile t; barrier extends to all
// waves. stage(t+3) -> slot (t-1)&3 whose readers all passed this barrier.
// One barrier per K-step; never vmcnt(0) mid-loop. LDS swizzle: 16B-block
// blk' = blk ^ ((row>>1)&3) on the GLOBAL source + on the ds_read address.
// ---------------------------------------------------------------------------
template<bool OUT_F32, int BMODE, int SWZ>
__global__ __launch_bounds__(512)
void gemm256(const u16* __restrict__ A, const u16* __restrict__ Bt,
             void* __restrict__ Cv,
             const float* __restrict__ bias, const float* __restrict__ bias2,
             float* __restrict__ lsum,
             int M, int N, int K, int lda, int ldb, float scale,
             long sA, long sB, long sC)
{
  int bxs = blockIdx.x, bys = blockIdx.y, bz = blockIdx.z;
  if (SWZ == 1) {
    const int lin  = blockIdx.x + gridDim.x * (blockIdx.y + gridDim.y * blockIdx.z);
    bz = lin & 7;
    const int rest = lin >> 3;
    bxs = rest % gridDim.x;
    bys = rest / gridDim.x;
  } else if (SWZ == 2) {
    const int gx = gridDim.x;
    int lin = blockIdx.x + gx * blockIdx.y;
    const int nb = gx * gridDim.y;
    const int q  = nb >> 3;
    lin = (lin & 7) * q + (lin >> 3);
    bxs = lin % gx;
    bys = lin / gx;
  }
  A  += (size_t)bz * sA;
  Bt += (size_t)bz * sB;
  if (BMODE >= 4) lsum += (size_t)bz * M;

  const int tid  = threadIdx.x;
  const int lane = tid & 63;
  const int w    = tid >> 6;
  const int wm   = w >> 2;          // 0..1  (M direction, 128 rows each)
  const int wn   = w & 3;           // 0..3  (N direction, 64 cols each)
  const int brow = bys * 256;
  const int bcol = bxs * 256;

  __shared__ u16 lds[4][2][256 * 32];   // [slot][A/B][row*32+col]  128 KiB

  const u16* gA = A  + (size_t)brow * lda;
  const u16* gB = Bt + (size_t)bcol * ldb;

  // per-thread staging descriptors: 2 rounds x (A,B); 16B chunk c = r*512+tid
  int c8[2], soffA[2], soffB[2];
#pragma unroll
  for (int r = 0; r < 2; ++r) {
    const int c    = r * 512 + tid;
    const int row  = c >> 2;
    const int blk  = c & 3;
    const int sblk = blk ^ ((row >> 1) & 3);   // inverse swizzle on source
    c8[r]    = c * 8;
    soffA[r] = row * lda + sblk * 8;
    soffB[r] = row * ldb + sblk * 8;
  }
  const int NT = K >> 5;

  f32x4 acc[8][4] = {};

  // prologue: stage tiles 0..2
#pragma unroll
  for (int tt = 0; tt < 3; ++tt) {
    const int kt = tt * 32;
#pragma unroll
    for (int r = 0; r < 2; ++r) load_lds16(gA + soffA[r] + kt, &lds[tt][0][c8[r]]);
#pragma unroll
    for (int r = 0; r < 2; ++r) load_lds16(gB + soffB[r] + kt, &lds[tt][1][c8[r]]);
  }
  __builtin_amdgcn_sched_barrier(0);

  // read addressing (HW-verified conflict-free): quarter kq = lane>>4 picks
  // k-block; rsw = (kq ^ ((lane>>1)&3))*8 matches the write-side swizzle.
  const int rsw   = ((lane >> 4) ^ ((lane >> 1) & 3)) * 8;
  const int arow0 = wm * 128 + (lane & 15);
  const int brow0 = wn * 64  + (lane & 15);

  for (int t = 0; t < NT; ++t) {
    if (t < NT - 2)       asm volatile("s_waitcnt vmcnt(8)" ::: "memory");
    else if (t == NT - 2) asm volatile("s_waitcnt vmcnt(4)" ::: "memory");
    else                  asm volatile("s_waitcnt vmcnt(0)" ::: "memory");
    __builtin_amdgcn_s_barrier();
    __builtin_amdgcn_sched_barrier(0);

    const u16* la = lds[t & 3][0];
    const u16* lb = lds[t & 3][1];
    bf16x8 av[8], bv[4];
#pragma unroll
    for (int m = 0; m < 8; ++m)
      av[m] = *(const bf16x8*)&la[(arow0 + m * 16) * 32 + rsw];
#pragma unroll
    for (int n = 0; n < 4; ++n)
      bv[n] = *(const bf16x8*)&lb[(brow0 + n * 16) * 32 + rsw];

    if (t + 3 < NT) {                      // stage tile t+3 into slot (t-1)&3
      const int kt = (t + 3) * 32, sl = (t + 3) & 3;
#pragma unroll
      for (int r = 0; r < 2; ++r) load_lds16(gA + soffA[r] + kt, &lds[sl][0][c8[r]]);
#pragma unroll
      for (int r = 0; r < 2; ++r) load_lds16(gB + soffB[r] + kt, &lds[sl][1][c8[r]]);
    }

    __builtin_amdgcn_s_setprio(1);
#pragma unroll
    for (int m = 0; m < 8; ++m)
#pragma unroll
      for (int n = 0; n < 4; ++n)
        acc[m][n] = __builtin_amdgcn_mfma_f32_16x16x32_bf16(av[m], bv[n], acc[m][n], 0, 0, 0);
    __builtin_amdgcn_s_setprio(0);
  }

  // epilogue: C/D layout col = lane&15, row = (lane>>4)*4 + j  [m89-verified]
  float* Cf = (float*)Cv + (size_t)bz * sC;
  u16*   Cb = (u16*)Cv   + (size_t)bz * sC;
  const int r0base  = brow + wm * 128 + ((lane >> 4) << 2);
  const int colbase = bcol + wn * 64  + (lane & 15);
#pragma unroll
  for (int m = 0; m < 8; ++m) {
    if (BMODE == 6) {
      // write E = exp(acc*scale) and accumulate per-row sums into lsum.
#pragma unroll
      for (int j = 0; j < 4; ++j) {
        const int row = r0base + m * 16 + j;
        float rp = 0.f;
#pragma unroll
        for (int n = 0; n < 4; ++n) {
          const int col = colbase + n * 16;
          const float e = __expf(acc[m][n][j] * scale);
          const u16 eb = f2bf(e);
          Cb[(size_t)row * N + col] = eb;
          rp += bf2f(eb);
        }
        rp += __shfl_xor(rp, 1);
        rp += __shfl_xor(rp, 2);
        rp += __shfl_xor(rp, 4);
        rp += __shfl_xor(rp, 8);
        if ((lane & 15) == 0) atomicAdd(&lsum[row], rp);
      }
    } else {
      float invl_j[4];
      if (BMODE == 4 || BMODE == 5) {
#pragma unroll
        for (int j = 0; j < 4; ++j)
          invl_j[j] = 1.0f / lsum[r0base + m * 16 + j];
      }
      const int r0 = r0base + m * 16;
#pragma unroll
      for (int n = 0; n < 4; ++n) {
        const int col = colbase + n * 16;
        float badd = 0.f;
        if (BMODE == 1 || BMODE == 4) badd = bias[col];
        if (BMODE == 3) badd = (col < (N >> 1)) ? bias[col] : bias2[col - (N >> 1)];
#pragma unroll
        for (int j = 0; j < 4; ++j) {
          const int row = r0 + j;
          float v = acc[m][n][j] * scale;
          if (BMODE == 4 || BMODE == 5) v *= invl_j[j];
          v += badd;
          if (BMODE == 2) v += bias[row];
          if (OUT_F32) Cf[(size_t)row * N + col] = v;
          else         Cb[(size_t)row * N + col] = f2bf(v);
        }
      }
    }
  }
}

// ---------------------------------------------------------------------------
// merged prep for the fused path: one dispatch does
//   [0,8192)        cvt X -> Xb (bf16)
//   [8192,8704)     cvt Wv -> Wvb
//   [8704,9728)     transpose Wq -> Wqt
//   [9728,10752)    transpose Wk -> Wkt
//   [10752,11776)   transpose Wo -> Wot
//   [11776,11792)   make_b2: b2 = bv@Wo + bo
//   [11792,11856)   zero l (16384 f32)
// all blocks 256 threads.
// ---------------------------------------------------------------------------
DEVINL void dev_cvt8(const float* in, u16* out, int i)
{
  const float4* in4 = (const float4*)in;
  float4 a = in4[2 * i], b = in4[2 * i + 1];
  u16x8 o;
  o[0] = f2bf(a.x); o[1] = f2bf(a.y); o[2] = f2bf(a.z); o[3] = f2bf(a.w);
  o[4] = f2bf(b.x); o[5] = f2bf(b.y); o[6] = f2bf(b.z); o[7] = f2bf(b.w);
  ((u16x8*)out)[i] = o;
}

__global__ __launch_bounds__(256)
void prep_fused(const float* __restrict__ X, const float* __restrict__ Wq,
                const float* __restrict__ Wk, const float* __restrict__ Wv,
                const float* __restrict__ Wo, const float* __restrict__ bv,
                const float* __restrict__ bo,
                u16* __restrict__ Xb, u16* __restrict__ Wvb,
                u16* __restrict__ Wqt, u16* __restrict__ Wkt,
                u16* __restrict__ Wot, float* __restrict__ b2,
                float* __restrict__ l)
{
  const int bid = blockIdx.x;
  const int tid = threadIdx.x;
  __shared__ float tile[32][33];
  __shared__ float red[4][64];

  if (bid < 8192) {                       // cvt X
    dev_cvt8(X, Xb, bid * 256 + tid);
  } else if (bid < 8704) {                // cvt Wv
    dev_cvt8(Wv, Wvb, (bid - 8192) * 256 + tid);
  } else if (bid < 11776) {               // transposes
    const int r  = bid - 8704;
    const int p  = r >> 10;               // 0 Wq, 1 Wk, 2 Wo
    const int pb = r & 1023;
    const float* W = p == 0 ? Wq : p == 1 ? Wk : Wo;
    u16*         T = p == 0 ? Wqt : p == 1 ? Wkt : Wot;
    const int e0 = (pb & 31) * 32, d0 = (pb >> 5) * 32;
    const int tx = tid & 31, ty = tid >> 5;
#pragma unroll
    for (int rr = ty; rr < 32; rr += 8)
      tile[rr][tx] = W[(size_t)(d0 + rr) * 1024 + e0 + tx];
    __syncthreads();
#pragma unroll
    for (int rr = ty; rr < 32; rr += 8)
      T[(size_t)(e0 + rr) * 1024 + d0 + tx] = f2bf(tile[tx][rr]);
  } else if (bid < 11792) {               // make_b2
    const int el = tid & 63;
    const int e  = (bid - 11776) * 64 + el;
    const int cg = tid >> 6;
    float s = 0.f;
    for (int c = cg; c < 1024; c += 4)
      s += bv[c] * Wo[(size_t)c * 1024 + e];
    red[cg][el] = s;
    __syncthreads();
    if (cg == 0)
      b2[e] = red[0][el] + red[1][el] + red[2][el] + red[3][el] + bo[e];
  } else {                                // zero l
    l[(bid - 11792) * 256 + tid] = 0.f;
  }
}

// out[i] = bf16(p[i] + p[i+n] + p[i+2n] + p[i+3n])  — split-K partial reduce
__global__ __launch_bounds__(256)
void reduce4_cvt(const float* __restrict__ p, u16* __restrict__ out, int n4)
{
  const int i = blockIdx.x * 256 + threadIdx.x;
  if (i >= n4) return;
  const float4* p4 = (const float4*)p;
  float4 a = p4[i], b = p4[i + (size_t)n4], c = p4[i + 2 * (size_t)n4], d = p4[i + 3 * (size_t)n4];
  ushort4 o;
  o.x = f2bf(a.x + b.x + c.x + d.x);
  o.y = f2bf(a.y + b.y + c.y + d.y);
  o.z = f2bf(a.z + b.z + c.z + d.z);
  o.w = f2bf(a.w + b.w + c.w + d.w);
  ((ushort4*)out)[i] = o;
}

// ---- standalone kernels kept for the fallback path ----
__global__ __launch_bounds__(256)
void cvt_f32_bf16(const float* __restrict__ in, u16* __restrict__ out, int n8)
{
  const int i = blockIdx.x * 256 + threadIdx.x;
  if (i >= n8) return;
  dev_cvt8(in, out, i);
}

__global__ __launch_bounds__(256)
void transpose_cvt(const float* __restrict__ W0, const float* __restrict__ W1,
                   const float* __restrict__ W2, const float* __restrict__ W3,
                   u16* __restrict__ T0, u16* __restrict__ T1,
                   u16* __restrict__ T2, u16* __restrict__ T3)
{
  const float* W = blockIdx.z == 0 ? W0 : blockIdx.z == 1 ? W1 : blockIdx.z == 2 ? W2 : W3;
  u16*         T = blockIdx.z == 0 ? T0 : blockIdx.z == 1 ? T1 : blockIdx.z == 2 ? T2 : T3;
  __shared__ float tile[32][33];
  const int d0 = blockIdx.y * 32, e0 = blockIdx.x * 32;
  const int tx = threadIdx.x, ty = threadIdx.y;
#pragma unroll
  for (int r = ty; r < 32; r += 8)
    tile[r][tx] = W[(size_t)(d0 + r) * 1024 + e0 + tx];
  __syncthreads();
#pragma unroll
  for (int r = ty; r < 32; r += 8)
    T[(size_t)(e0 + r) * 1024 + d0 + tx] = f2bf(tile[tx][r]);
}

__global__ __launch_bounds__(256)
void zero_f32(float* __restrict__ p, int n)
{
  const int i = blockIdx.x * 256 + threadIdx.x;
  if (i < n) p[i] = 0.f;
}

// ---------------------------------------------------------------------------
extern "C" void kernel_launch(void* const* d_in, const int* in_sizes, int n_in,
                              void* d_out, int out_size, void* d_ws, size_t ws_size,
                              hipStream_t stream)
{
  const float* X  = (const float*)d_in[0];
  const float* Wq = (const float*)d_in[1];
  const float* bq = (const float*)d_in[2];
  const float* Wk = (const float*)d_in[3];
  const float* bk = (const float*)d_in[4];
  const float* Wv = (const float*)d_in[5];
  const float* bv = (const float*)d_in[6];
  const float* Wo = (const float*)d_in[7];
  const float* bo = (const float*)d_in[8];

  constexpr int B = 8, N = 2048, D = 1024;
  constexpr size_t TOK = (size_t)B * N;        // 16384
  constexpr size_t SZX = TOK * D;              // 16,777,216 elems
  constexpr size_t SZW = (size_t)D * D;

  const size_t FUSED_BYTES = (5 * SZX + 5 * SZW + 34816) * sizeof(u16);   // ~178 MB

  if (ws_size >= FUSED_BYTES) {
    // ---- fused path: out = E @ (X@(Wv@Wo))^T / l + (bv@Wo + bo) ----
    u16* QK  = (u16*)d_ws;            // [16384][2048]: cols 0..1023 Q, rest K
    u16* Vpt = QK  + 2 * SZX;         // V'^T = (X@W2)^T  [B][D][N]
    u16* E   = Vpt + SZX;             // exp(scores) bf16 [B][N][N]
    u16* Xb  = E;                     // overlay: Xb dead before E is written
    u16* Wqt = E   + 2 * SZX;
    u16* Wkt = Wqt + SZW;
    u16* Wot = Wkt + SZW;
    u16* Wvb = Wot + SZW;             // Wv bf16, NOT transposed
    u16* W2t = Wvb + SZW;             // (Wv@Wo)^T bf16
    float* b2 = (float*)(W2t + SZW);  // 1024 f32
    float* l  = b2 + 1024;            // 16384 f32 row sums
    float* W2f = (float*)QK;          // 4 x SZW f32 split-K partials (QK dead)

    // 1. all prep in one dispatch
    prep_fused<<<dim3(11856), 256, 0, stream>>>(
        X, Wq, Wk, Wv, Wo, bv, bo, Xb, Wvb, Wqt, Wkt, Wot, b2, l);

    // 2. W2 split-K x4 -> f32 partials, then reduce+cvt -> W2t
    gemm256<true, 0, 0><<<dim3(4, 4, 4), 512, 0, stream>>>(
        Wot, Wvb, W2f, nullptr, nullptr, nullptr, D, D, 256, D, D, 1.f,
        256, 256, (long)SZW);
    reduce4_cvt<<<dim3((unsigned)(SZW / 4 / 256)), 256, 0, stream>>>(W2f, W2t, (int)(SZW / 4));

    // 3. fused Q,K projection: [16384,2048] = X @ [Wq|Wk] (+ bq|bk)
    //    (overwrites W2f; xy-chunk XCD swizzle for A-panel L2 reuse)
    gemm256<false, 3, 2><<<dim3(8, 64, 1), 512, 0, stream>>>(
        Xb, Wqt, QK, bq, bk, nullptr, (int)TOK, 2 * D, D, D, D, 1.f, 0, 0, 0);

    // 4. V'^T[b] = W2t @ Xb[b]^T   [D, N] per batch (no bias)
    gemm256<false, 0, 1><<<dim3(8, 4, 8), 512, 0, stream>>>(
        W2t, Xb, Vpt, nullptr, nullptr, nullptr, D, N, D, D, D, 1.f,
        0, (long)N * D, (long)D * N);

    // 5. E[b] = exp(Q[b] @ K[b]^T / 32), row sums into l  (E overlays dead Xb)
    gemm256<false, 6, 1><<<dim3(8, 8, 8), 512, 0, stream>>>(
        QK, QK + D, E, nullptr, nullptr, l, N, N, D, 2 * D, 2 * D, 0.03125f,
        (long)N * 2 * D, (long)N * 2 * D, (long)N * N);

    // 6. out[b] = (E[b] @ V'^T[b]^T) / l + b2   f32 -> d_out
    gemm256<true, 4, 1><<<dim3(4, 8, 8), 512, 0, stream>>>(
        E, Vpt, d_out, b2, nullptr, l, N, D, N, N, N, 1.f,
        (long)N * N, (long)D * N, (long)N * D);
  } else {
    // ---- fallback (round-4 flow + softmax-free l scheme) ----
    if (ws_size < (4 * SZX + 4 * SZW) * sizeof(u16) + 65536) return;
    u16* Xb  = (u16*)d_ws;            // X bf16; later reused as attn_out (AO)
    u16* Wqt = Xb  + SZX;
    u16* Wkt = Wqt + SZW;
    u16* Wvt = Wkt + SZW;
    u16* Wot = Wvt + SZW;
    u16* QK  = Wot + SZW;
    u16* Vt  = QK  + 2 * SZX;         // [B][D][N]
    float* l = (float*)(Vt + SZX);    // 16384 f32
    u16* E   = (u16*)d_out;           // exp(scores) bf16 in d_out
    u16* AO  = Xb;

    cvt_f32_bf16<<<dim3((unsigned)(SZX / 8 / 256)), 256, 0, stream>>>(X, Xb, (int)(SZX / 8));
    transpose_cvt<<<dim3(32, 32, 4), dim3(32, 8), 0, stream>>>(Wq, Wk, Wv, Wo, Wqt, Wkt, Wvt, Wot);

    gemm256<false, 3, 0><<<dim3(8, 64, 1), 512, 0, stream>>>(
        Xb, Wqt, QK, bq, bk, nullptr, (int)TOK, 2 * D, D, D, D, 1.f, 0, 0, 0);

    gemm256<false, 2, 1><<<dim3(8, 4, 8), 512, 0, stream>>>(
        Wvt, Xb, Vt, bv, nullptr, nullptr, D, N, D, D, D, 1.f,
        0, (long)N * D, (long)D * N);

    zero_f32<<<dim3(64), 256, 0, stream>>>(l, (int)TOK);

    gemm256<false, 6, 1><<<dim3(8, 8, 8), 512, 0, stream>>>(
        QK, QK + D, E, nullptr, nullptr, l, N, N, D, 2 * D, 2 * D, 0.03125f,
        (long)N * 2 * D, (long)N * 2 * D, (long)N * N);

    gemm256<false, 5, 1><<<dim3(4, 8, 8), 512, 0, stream>>>(
        E, Vt, AO, nullptr, nullptr, l, N, D, N, N, N, 1.f,
        (long)N * N, (long)D * N, (long)N * D);

    gemm256<true, 1, 0><<<dim3(4, 64, 1), 512, 0, stream>>>(
        AO, Wot, d_out, bo, nullptr, nullptr, (int)TOK, D, D, D, D, 1.f, 0, 0, 0);
  }
}

// Round 9
// 304.762 us; speedup vs baseline: 1.3244x; 1.2364x over previous
//
#include <hip/hip_runtime.h>
#include <hip/hip_bf16.h>
#include <stdint.h>

#define DEVINL __device__ __forceinline__

typedef unsigned short u16;
typedef __attribute__((ext_vector_type(8))) short bf16x8;   // 8 bf16 = 4 VGPRs (MFMA A/B frag)
typedef __attribute__((ext_vector_type(4))) float f32x4;    // MFMA C/D frag
typedef __attribute__((ext_vector_type(8))) unsigned short u16x8;

DEVINL u16 f2bf(float f) {               // round-to-nearest-even f32 -> bf16
  union { float f; unsigned u; } x; x.f = f;
  unsigned r = x.u + 0x7fffu + ((x.u >> 16) & 1u);
  return (u16)(r >> 16);
}
DEVINL float bf2f(u16 u) {
  union { float f; unsigned u; } x; x.u = ((unsigned)u) << 16; return x.f;
}

DEVINL void load_lds16(const u16* g, u16* l) {
  // async global->LDS, 16B per lane; LDS dest = wave-uniform base + lane*16
  __builtin_amdgcn_global_load_lds(
      (const __attribute__((address_space(1))) void*)g,
      (__attribute__((address_space(3))) void*)l, 16, 0, 0);
}

// ---------------------------------------------------------------------------
// C[M,N] = A[M,K] @ Bt[N,K]^T * scale (+ epilogue)    A,Bt bf16; C bf16 or f32
// BMODE: 0 none | 1 +bias[col] | 2 +bias[row] | 3 dual col bias split at N/2
//        4 *1/lsum[row] + bias[col] (f32 out) | 5 *1/lsum[row] (bf16 out)
//        6 E=exp(acc*scale) bf16 out + atomicAdd row sums into lsum
// SWZ:   0 none | 1 batch-coherent XCD remap (needs gridDim.z == 8) |
//        2 flat xy chunk remap (needs (gx*gy)%8==0, gz==1)
// Split-K use: pass sA=sB=K_chunk, sC = slab stride, gridDim.z = n_splits.
// 256x256 tile, BK=32, ring-4 LDS slots, counted-vmcnt pipeline (depth 3),
// 16x16x32 MFMA (HW-verified 0 bank conflicts).
// 512 threads = 8 waves (2M x 4N), wave tile 128x64 -> acc[8][4] of f32x4.
//
// Race-freedom: iteration t reads slot t&3 after {vmcnt(8); s_barrier}:
// vmcnt(8) retires this wave's 4 loads of tile t; barrier extends to all
// waves. stage(t+3) -> slot (t-1)&3 whose readers all passed this barrier.
// One barrier per K-step; never vmcnt(0) mid-loop. LDS swizzle: 16B-block
// blk' = blk ^ ((row>>1)&3) on the GLOBAL source + on the ds_read address.
// ---------------------------------------------------------------------------
template<bool OUT_F32, int BMODE, int SWZ>
__global__ __launch_bounds__(512)
void gemm256(const u16* __restrict__ A, const u16* __restrict__ Bt,
             void* __restrict__ Cv,
             const float* __restrict__ bias, const float* __restrict__ bias2,
             float* __restrict__ lsum,
             int M, int N, int K, int lda, int ldb, float scale,
             long sA, long sB, long sC)
{
  int bxs = blockIdx.x, bys = blockIdx.y, bz = blockIdx.z;
  if (SWZ == 1) {
    const int lin  = blockIdx.x + gridDim.x * (blockIdx.y + gridDim.y * blockIdx.z);
    bz = lin & 7;
    const int rest = lin >> 3;
    bxs = rest % gridDim.x;
    bys = rest / gridDim.x;
  } else if (SWZ == 2) {
    const int gx = gridDim.x;
    int lin = blockIdx.x + gx * blockIdx.y;
    const int nb = gx * gridDim.y;
    const int q  = nb >> 3;
    lin = (lin & 7) * q + (lin >> 3);
    bxs = lin % gx;
    bys = lin / gx;
  }
  A  += (size_t)bz * sA;
  Bt += (size_t)bz * sB;
  if (BMODE >= 4) lsum += (size_t)bz * M;

  const int tid  = threadIdx.x;
  const int lane = tid & 63;
  const int w    = tid >> 6;
  const int wm   = w >> 2;          // 0..1  (M direction, 128 rows each)
  const int wn   = w & 3;           // 0..3  (N direction, 64 cols each)
  const int brow = bys * 256;
  const int bcol = bxs * 256;

  __shared__ u16 lds[4][2][256 * 32];   // [slot][A/B][row*32+col]  128 KiB

  const u16* gA = A  + (size_t)brow * lda;
  const u16* gB = Bt + (size_t)bcol * ldb;

  // per-thread staging descriptors: 2 rounds x (A,B); 16B chunk c = r*512+tid
  int c8[2], soffA[2], soffB[2];
#pragma unroll
  for (int r = 0; r < 2; ++r) {
    const int c    = r * 512 + tid;
    const int row  = c >> 2;
    const int blk  = c & 3;
    const int sblk = blk ^ ((row >> 1) & 3);   // inverse swizzle on source
    c8[r]    = c * 8;
    soffA[r] = row * lda + sblk * 8;
    soffB[r] = row * ldb + sblk * 8;
  }
  const int NT = K >> 5;

  f32x4 acc[8][4] = {};

  // prologue: stage tiles 0..2
#pragma unroll
  for (int tt = 0; tt < 3; ++tt) {
    const int kt = tt * 32;
#pragma unroll
    for (int r = 0; r < 2; ++r) load_lds16(gA + soffA[r] + kt, &lds[tt][0][c8[r]]);
#pragma unroll
    for (int r = 0; r < 2; ++r) load_lds16(gB + soffB[r] + kt, &lds[tt][1][c8[r]]);
  }
  __builtin_amdgcn_sched_barrier(0);

  // read addressing (HW-verified conflict-free): quarter kq = lane>>4 picks
  // k-block; rsw = (kq ^ ((lane>>1)&3))*8 matches the write-side swizzle.
  const int rsw   = ((lane >> 4) ^ ((lane >> 1) & 3)) * 8;
  const int arow0 = wm * 128 + (lane & 15);
  const int brow0 = wn * 64  + (lane & 15);

  for (int t = 0; t < NT; ++t) {
    if (t < NT - 2)       asm volatile("s_waitcnt vmcnt(8)" ::: "memory");
    else if (t == NT - 2) asm volatile("s_waitcnt vmcnt(4)" ::: "memory");
    else                  asm volatile("s_waitcnt vmcnt(0)" ::: "memory");
    __builtin_amdgcn_s_barrier();
    __builtin_amdgcn_sched_barrier(0);

    const u16* la = lds[t & 3][0];
    const u16* lb = lds[t & 3][1];
    bf16x8 av[8], bv[4];
#pragma unroll
    for (int m = 0; m < 8; ++m)
      av[m] = *(const bf16x8*)&la[(arow0 + m * 16) * 32 + rsw];
#pragma unroll
    for (int n = 0; n < 4; ++n)
      bv[n] = *(const bf16x8*)&lb[(brow0 + n * 16) * 32 + rsw];

    if (t + 3 < NT) {                      // stage tile t+3 into slot (t-1)&3
      const int kt = (t + 3) * 32, sl = (t + 3) & 3;
#pragma unroll
      for (int r = 0; r < 2; ++r) load_lds16(gA + soffA[r] + kt, &lds[sl][0][c8[r]]);
#pragma unroll
      for (int r = 0; r < 2; ++r) load_lds16(gB + soffB[r] + kt, &lds[sl][1][c8[r]]);
    }

    __builtin_amdgcn_s_setprio(1);
#pragma unroll
    for (int m = 0; m < 8; ++m)
#pragma unroll
      for (int n = 0; n < 4; ++n)
        acc[m][n] = __builtin_amdgcn_mfma_f32_16x16x32_bf16(av[m], bv[n], acc[m][n], 0, 0, 0);
    __builtin_amdgcn_s_setprio(0);
  }

  // epilogue: C/D layout col = lane&15, row = (lane>>4)*4 + j  [m89-verified]
  float* Cf = (float*)Cv + (size_t)bz * sC;
  u16*   Cb = (u16*)Cv   + (size_t)bz * sC;
  const int r0base  = brow + wm * 128 + ((lane >> 4) << 2);
  const int colbase = bcol + wn * 64  + (lane & 15);
#pragma unroll
  for (int m = 0; m < 8; ++m) {
    if (BMODE == 6) {
      // write E = exp(acc*scale) and accumulate per-row sums into lsum.
#pragma unroll
      for (int j = 0; j < 4; ++j) {
        const int row = r0base + m * 16 + j;
        float rp = 0.f;
#pragma unroll
        for (int n = 0; n < 4; ++n) {
          const int col = colbase + n * 16;
          const float e = __expf(acc[m][n][j] * scale);
          const u16 eb = f2bf(e);
          Cb[(size_t)row * N + col] = eb;
          rp += bf2f(eb);
        }
        rp += __shfl_xor(rp, 1);
        rp += __shfl_xor(rp, 2);
        rp += __shfl_xor(rp, 4);
        rp += __shfl_xor(rp, 8);
        if ((lane & 15) == 0) atomicAdd(&lsum[row], rp);
      }
    } else {
      float invl_j[4];
      if (BMODE == 4 || BMODE == 5) {
#pragma unroll
        for (int j = 0; j < 4; ++j)
          invl_j[j] = 1.0f / lsum[r0base + m * 16 + j];
      }
      const int r0 = r0base + m * 16;
#pragma unroll
      for (int n = 0; n < 4; ++n) {
        const int col = colbase + n * 16;
        float badd = 0.f;
        if (BMODE == 1 || BMODE == 4) badd = bias[col];
        if (BMODE == 3) badd = (col < (N >> 1)) ? bias[col] : bias2[col - (N >> 1)];
#pragma unroll
        for (int j = 0; j < 4; ++j) {
          const int row = r0 + j;
          float v = acc[m][n][j] * scale;
          if (BMODE == 4 || BMODE == 5) v *= invl_j[j];
          v += badd;
          if (BMODE == 2) v += bias[row];
          if (OUT_F32) Cf[(size_t)row * N + col] = v;
          else         Cb[(size_t)row * N + col] = f2bf(v);
        }
      }
    }
  }
}

// ---------------------------------------------------------------------------
// merged prep for the fused path (all blocks 256 threads):
//   [0,8192)        cvt X -> Xb (bf16)
//   [8192,8704)     cvt Wv -> Wvb
//   [8704,11776)    transpose Wq/Wk/Wo -> Wqt/Wkt/Wot
//   [11776,12032)   b2 partials: pb2[by][e] = sum_{c in by-chunk} bv[c]*Wo[c][e]
//                   (256 blocks: by=chunk of 64 c-rows, bx=chunk of 64 e-cols;
//                    depth-16 coalesced load chain — NOT the old 256-deep GEMV)
//   [12032,12096)   zero l (16384 f32)
// ---------------------------------------------------------------------------
DEVINL void dev_cvt8(const float* in, u16* out, int i)
{
  const float4* in4 = (const float4*)in;
  float4 a = in4[2 * i], b = in4[2 * i + 1];
  u16x8 o;
  o[0] = f2bf(a.x); o[1] = f2bf(a.y); o[2] = f2bf(a.z); o[3] = f2bf(a.w);
  o[4] = f2bf(b.x); o[5] = f2bf(b.y); o[6] = f2bf(b.z); o[7] = f2bf(b.w);
  ((u16x8*)out)[i] = o;
}

__global__ __launch_bounds__(256)
void prep_fused(const float* __restrict__ X, const float* __restrict__ Wq,
                const float* __restrict__ Wk, const float* __restrict__ Wv,
                const float* __restrict__ Wo, const float* __restrict__ bv,
                u16* __restrict__ Xb, u16* __restrict__ Wvb,
                u16* __restrict__ Wqt, u16* __restrict__ Wkt,
                u16* __restrict__ Wot, float* __restrict__ pb2,
                float* __restrict__ l)
{
  const int bid = blockIdx.x;
  const int tid = threadIdx.x;
  __shared__ float tile[32][33];
  __shared__ float red[4][64];

  if (bid < 8192) {                       // cvt X
    dev_cvt8(X, Xb, bid * 256 + tid);
  } else if (bid < 8704) {                // cvt Wv
    dev_cvt8(Wv, Wvb, (bid - 8192) * 256 + tid);
  } else if (bid < 11776) {               // transposes
    const int r  = bid - 8704;
    const int p  = r >> 10;               // 0 Wq, 1 Wk, 2 Wo
    const int pb = r & 1023;
    const float* W = p == 0 ? Wq : p == 1 ? Wk : Wo;
    u16*         T = p == 0 ? Wqt : p == 1 ? Wkt : Wot;
    const int e0 = (pb & 31) * 32, d0 = (pb >> 5) * 32;
    const int tx = tid & 31, ty = tid >> 5;
#pragma unroll
    for (int rr = ty; rr < 32; rr += 8)
      tile[rr][tx] = W[(size_t)(d0 + rr) * 1024 + e0 + tx];
    __syncthreads();
#pragma unroll
    for (int rr = ty; rr < 32; rr += 8)
      T[(size_t)(e0 + rr) * 1024 + d0 + tx] = f2bf(tile[tx][rr]);
  } else if (bid < 12032) {               // b2 partials (split 16c x 16e)
    const int r  = bid - 11776;
    const int by = r >> 4;                // c-chunk: rows [by*64, by*64+64)
    const int bx = r & 15;                // e-chunk: cols [bx*64, bx*64+64)
    const int el = tid & 63;
    const int e  = bx * 64 + el;
    const int cg = tid >> 6;              // 0..3
    const int c0 = by * 64 + cg * 16;
    float s = 0.f;
#pragma unroll
    for (int i = 0; i < 16; ++i) {
      const int c = c0 + i;
      s += bv[c] * Wo[(size_t)c * 1024 + e];
    }
    red[cg][el] = s;
    __syncthreads();
    if (cg == 0)
      pb2[(size_t)by * 1024 + e] = red[0][el] + red[1][el] + red[2][el] + red[3][el];
  } else {                                // zero l
    l[(bid - 12032) * 256 + tid] = 0.f;
  }
}

// blocks [0,1024): W2t[i] = bf16(sum of 4 split-K f32 partials)
// blocks [1024,1028): b2[e] = bo[e] + sum_{by<16} pb2[by][e]
__global__ __launch_bounds__(256)
void reduce_misc(const float* __restrict__ p, u16* __restrict__ out, int n4,
                 const float* __restrict__ pb2, const float* __restrict__ bo,
                 float* __restrict__ b2)
{
  const int bid = blockIdx.x;
  if (bid < 1024) {
    const int i = bid * 256 + threadIdx.x;
    if (i >= n4) return;
    const float4* p4 = (const float4*)p;
    float4 a = p4[i], b = p4[i + (size_t)n4], c = p4[i + 2 * (size_t)n4], d = p4[i + 3 * (size_t)n4];
    ushort4 o;
    o.x = f2bf(a.x + b.x + c.x + d.x);
    o.y = f2bf(a.y + b.y + c.y + d.y);
    o.z = f2bf(a.z + b.z + c.z + d.z);
    o.w = f2bf(a.w + b.w + c.w + d.w);
    ((ushort4*)out)[i] = o;
  } else {
    const int e = (bid - 1024) * 256 + threadIdx.x;
    if (e >= 1024) return;
    float s = bo[e];
#pragma unroll
    for (int by = 0; by < 16; ++by) s += pb2[(size_t)by * 1024 + e];
    b2[e] = s;
  }
}

// ---- standalone kernels kept for the fallback path ----
__global__ __launch_bounds__(256)
void cvt_f32_bf16(const float* __restrict__ in, u16* __restrict__ out, int n8)
{
  const int i = blockIdx.x * 256 + threadIdx.x;
  if (i >= n8) return;
  dev_cvt8(in, out, i);
}

__global__ __launch_bounds__(256)
void transpose_cvt(const float* __restrict__ W0, const float* __restrict__ W1,
                   const float* __restrict__ W2, const float* __restrict__ W3,
                   u16* __restrict__ T0, u16* __restrict__ T1,
                   u16* __restrict__ T2, u16* __restrict__ T3)
{
  const float* W = blockIdx.z == 0 ? W0 : blockIdx.z == 1 ? W1 : blockIdx.z == 2 ? W2 : W3;
  u16*         T = blockIdx.z == 0 ? T0 : blockIdx.z == 1 ? T1 : blockIdx.z == 2 ? T2 : T3;
  __shared__ float tile[32][33];
  const int d0 = blockIdx.y * 32, e0 = blockIdx.x * 32;
  const int tx = threadIdx.x, ty = threadIdx.y;
#pragma unroll
  for (int r = ty; r < 32; r += 8)
    tile[r][tx] = W[(size_t)(d0 + r) * 1024 + e0 + tx];
  __syncthreads();
#pragma unroll
  for (int r = ty; r < 32; r += 8)
    T[(size_t)(e0 + r) * 1024 + d0 + tx] = f2bf(tile[tx][r]);
}

__global__ __launch_bounds__(256)
void zero_f32(float* __restrict__ p, int n)
{
  const int i = blockIdx.x * 256 + threadIdx.x;
  if (i < n) p[i] = 0.f;
}

// ---------------------------------------------------------------------------
extern "C" void kernel_launch(void* const* d_in, const int* in_sizes, int n_in,
                              void* d_out, int out_size, void* d_ws, size_t ws_size,
                              hipStream_t stream)
{
  const float* X  = (const float*)d_in[0];
  const float* Wq = (const float*)d_in[1];
  const float* bq = (const float*)d_in[2];
  const float* Wk = (const float*)d_in[3];
  const float* bk = (const float*)d_in[4];
  const float* Wv = (const float*)d_in[5];
  const float* bv = (const float*)d_in[6];
  const float* Wo = (const float*)d_in[7];
  const float* bo = (const float*)d_in[8];

  constexpr int B = 8, N = 2048, D = 1024;
  constexpr size_t TOK = (size_t)B * N;        // 16384
  constexpr size_t SZX = TOK * D;              // 16,777,216 elems
  constexpr size_t SZW = (size_t)D * D;

  // 5*SZX + 5*SZW bf16 + b2(4KB) + l(64KB) + pb2(64KB)
  const size_t FUSED_BYTES = (5 * SZX + 5 * SZW + 67584) * sizeof(u16);   // ~178 MB

  if (ws_size >= FUSED_BYTES) {
    // ---- fused path: out = E @ (X@(Wv@Wo))^T / l + (bv@Wo + bo) ----
    u16* QK  = (u16*)d_ws;            // [16384][2048]: cols 0..1023 Q, rest K
    u16* Vpt = QK  + 2 * SZX;         // V'^T = (X@W2)^T  [B][D][N]
    u16* E   = Vpt + SZX;             // exp(scores) bf16 [B][N][N]
    u16* Xb  = E;                     // overlay: Xb dead before E is written
    u16* Wqt = E   + 2 * SZX;
    u16* Wkt = Wqt + SZW;
    u16* Wot = Wkt + SZW;
    u16* Wvb = Wot + SZW;             // Wv bf16, NOT transposed
    u16* W2t = Wvb + SZW;             // (Wv@Wo)^T bf16
    float* b2  = (float*)(W2t + SZW); // 1024 f32
    float* l   = b2 + 1024;           // 16384 f32 row sums
    float* pb2 = l + TOK;             // 16x1024 f32 b2 partials
    float* W2f = (float*)QK;          // 4 x SZW f32 split-K partials (QK dead)

    // 1. all prep in one dispatch (incl. depth-16 b2 partials)
    prep_fused<<<dim3(12096), 256, 0, stream>>>(
        X, Wq, Wk, Wv, Wo, bv, Xb, Wvb, Wqt, Wkt, Wot, pb2, l);

    // 2. W2 split-K x4 -> f32 partials
    gemm256<true, 0, 0><<<dim3(4, 4, 4), 512, 0, stream>>>(
        Wot, Wvb, W2f, nullptr, nullptr, nullptr, D, D, 256, D, D, 1.f,
        256, 256, (long)SZW);

    // 3. reduce W2 partials -> W2t (bf16) and finalize b2 = bo + sum(pb2)
    reduce_misc<<<dim3(1028), 256, 0, stream>>>(
        W2f, W2t, (int)(SZW / 4), pb2, bo, b2);

    // 4. fused Q,K projection: [16384,2048] = X @ [Wq|Wk] (+ bq|bk)
    //    (overwrites W2f; xy-chunk XCD swizzle for A-panel L2 reuse)
    gemm256<false, 3, 2><<<dim3(8, 64, 1), 512, 0, stream>>>(
        Xb, Wqt, QK, bq, bk, nullptr, (int)TOK, 2 * D, D, D, D, 1.f, 0, 0, 0);

    // 5. V'^T[b] = W2t @ Xb[b]^T   [D, N] per batch (no bias)
    gemm256<false, 0, 1><<<dim3(8, 4, 8), 512, 0, stream>>>(
        W2t, Xb, Vpt, nullptr, nullptr, nullptr, D, N, D, D, D, 1.f,
        0, (long)N * D, (long)D * N);

    // 6. E[b] = exp(Q[b] @ K[b]^T / 32), row sums into l  (E overlays dead Xb)
    gemm256<false, 6, 1><<<dim3(8, 8, 8), 512, 0, stream>>>(
        QK, QK + D, E, nullptr, nullptr, l, N, N, D, 2 * D, 2 * D, 0.03125f,
        (long)N * 2 * D, (long)N * 2 * D, (long)N * N);

    // 7. out[b] = (E[b] @ V'^T[b]^T) / l + b2   f32 -> d_out
    gemm256<true, 4, 1><<<dim3(4, 8, 8), 512, 0, stream>>>(
        E, Vpt, d_out, b2, nullptr, l, N, D, N, N, N, 1.f,
        (long)N * N, (long)D * N, (long)N * D);
  } else {
    // ---- fallback (round-4 flow + softmax-free l scheme) ----
    if (ws_size < (4 * SZX + 4 * SZW) * sizeof(u16) + 65536) return;
    u16* Xb  = (u16*)d_ws;            // X bf16; later reused as attn_out (AO)
    u16* Wqt = Xb  + SZX;
    u16* Wkt = Wqt + SZW;
    u16* Wvt = Wkt + SZW;
    u16* Wot = Wvt + SZW;
    u16* QK  = Wot + SZW;
    u16* Vt  = QK  + 2 * SZX;         // [B][D][N]
    float* l = (float*)(Vt + SZX);    // 16384 f32
    u16* E   = (u16*)d_out;           // exp(scores) bf16 in d_out
    u16* AO  = Xb;

    cvt_f32_bf16<<<dim3((unsigned)(SZX / 8 / 256)), 256, 0, stream>>>(X, Xb, (int)(SZX / 8));
    transpose_cvt<<<dim3(32, 32, 4), dim3(32, 8), 0, stream>>>(Wq, Wk, Wv, Wo, Wqt, Wkt, Wvt, Wot);

    gemm256<false, 3, 0><<<dim3(8, 64, 1), 512, 0, stream>>>(
        Xb, Wqt, QK, bq, bk, nullptr, (int)TOK, 2 * D, D, D, D, 1.f, 0, 0, 0);

    gemm256<false, 2, 1><<<dim3(8, 4, 8), 512, 0, stream>>>(
        Wvt, Xb, Vt, bv, nullptr, nullptr, D, N, D, D, D, 1.f,
        0, (long)N * D, (long)D * N);

    zero_f32<<<dim3(64), 256, 0, stream>>>(l, (int)TOK);

    gemm256<false, 6, 1><<<dim3(8, 8, 8), 512, 0, stream>>>(
        QK, QK + D, E, nullptr, nullptr, l, N, N, D, 2 * D, 2 * D, 0.03125f,
        (long)N * 2 * D, (long)N * 2 * D, (long)N * N);

    gemm256<false, 5, 1><<<dim3(4, 8, 8), 512, 0, stream>>>(
        E, Vt, AO, nullptr, nullptr, l, N, D, N, N, N, 1.f,
        (long)N * N, (long)D * N, (long)N * D);

    gemm256<true, 1, 0><<<dim3(4, 64, 1), 512, 0, stream>>>(
        AO, Wot, d_out, bo, nullptr, nullptr, (int)TOK, D, D, D, D, 1.f, 0, 0, 0);
  }
}